// Round 1
// baseline (113.856 us; speedup 1.0000x reference)
//
#include <hip/hip_runtime.h>
#include <hip/hip_bf16.h>

// Problem constants (fixed by reference):
//   x[N=8][INC=32][INN=50000] fp32, A[OUTN=8192][MAXD=16] int32,
//   mask[OUTN][MAXD][1] fp32, weight[INC=32][OUTC=32] fp32, bias[OUTC=32][OUTN=8192]
//   out[N=8][OUTC=32][OUTN=8192] fp32
// K1: transpose x -> xt[INN][256] bf16 (row j = n*32+c).  K2: gather+pool+matmul fp32.
// R6: K2 MLP fix. Previous gather interleaved ds_read/global_load/FMA per d ->
//     compiler kept few loads in flight -> latency-bound at ~half BW. Now each
//     wave-group issues ALL 16 row loads into a register batch (8 KB in flight
//     per wave) before any FMA, and TO=16->8 doubles the grid to 1024 blocks
//     (up to 4 blocks/CU). K1 unchanged from R5 for attribution.

#define INN   50000
#define NR    256        // N*INC rows
#define OUTN  8192
#define MAXD  16
#define TO    8          // output nodes per block in K2

static __device__ __forceinline__ float bf2f(unsigned short u) {
    return __uint_as_float(((unsigned int)u) << 16);
}

// ---------------- Kernel 1: transpose x[256][50000] -> xt_bf16[50000][256] ----
// 64(i) x 64(r) tile, float4 loads along i, ushort4 (bf16x4) stores along r.
// LDS pitch 65: load-scatter and store-gather are <=2-way bank-aliased (free).
__global__ __launch_bounds__(256) void transpose_x(const float* __restrict__ x,
                                                   unsigned short* __restrict__ xt) {
    __shared__ float tile[64 * 65];
    const int t  = threadIdx.x;
    const int i0 = blockIdx.x * 64;   // column (INN) tile base
    const int r0 = blockIdx.y * 64;   // row tile base (always < 256)

    // ---- load: lanes sweep i (coalesced float4), 16 rows per k-step
    {
        const int i4l = t & 15;        // which float4 within the 64-wide i tile
        const int rl0 = t >> 4;        // row within tile
        const float4* x4 = (const float4*)x;
        const int i4base = (i0 >> 2) + i4l;
        const bool iv = (i4base < (INN / 4));   // INN % 4 == 0
        for (int k = 0; k < 4; ++k) {
            const int rl = rl0 + 16 * k;
            float4 v = iv ? x4[(size_t)(r0 + rl) * (INN / 4) + i4base]
                          : make_float4(0.f, 0.f, 0.f, 0.f);
            const int ib = i4l * 4;
            tile[(ib + 0) * 65 + rl] = v.x;
            tile[(ib + 1) * 65 + rl] = v.y;
            tile[(ib + 2) * 65 + rl] = v.z;
            tile[(ib + 3) * 65 + rl] = v.w;
        }
    }
    __syncthreads();
    // ---- store: lanes sweep r (coalesced ushort4 = 8B/lane)
    {
        const int r4l = t & 15;
        const int il0 = t >> 4;
        for (int k = 0; k < 4; ++k) {
            const int il = il0 + 16 * k;
            const int i  = i0 + il;
            if (i < INN) {
                ushort4 b;
                b.x = __bfloat16_as_ushort(__float2bfloat16(tile[il * 65 + r4l * 4 + 0]));
                b.y = __bfloat16_as_ushort(__float2bfloat16(tile[il * 65 + r4l * 4 + 1]));
                b.z = __bfloat16_as_ushort(__float2bfloat16(tile[il * 65 + r4l * 4 + 2]));
                b.w = __bfloat16_as_ushort(__float2bfloat16(tile[il * 65 + r4l * 4 + 3]));
                *(ushort4*)&xt[(size_t)i * NR + r0 + 4 * r4l] = b;
            }
        }
    }
}

// ---------------- Kernel 2: gather + masked pool + 32x32 matmul + bias ------
// One block = 8 output nodes, 512 threads (8 wave-groups x 1 node). Grid = 1024
// blocks. Each wave-group issues its 16 row loads (8 KB) back-to-back into
// registers before any FMA: MLP is guaranteed at source level, not left to the
// scheduler. Phase 2 on t<256 only (R2 store pattern preserved per node count).
__global__ __launch_bounds__(512) void gather_gemm(const unsigned short* __restrict__ xt,
                                                   const int*   __restrict__ A,
                                                   const float* __restrict__ mask,
                                                   const float* __restrict__ W,
                                                   const float* __restrict__ bias,
                                                   float* __restrict__ out) {
    // pooled pitch 260: 16B-aligned rows; every LDS op <=2-way aliased (free).
    __shared__ float pooled[TO * 260];
    __shared__ float Wt[32 * 36];      // Wt[cd][c], pitch 36 (16B aligned rows)
    __shared__ int   Ash[TO * MAXD];
    __shared__ float Msh[TO * MAXD];

    const int t  = threadIdx.x;
    const int o0 = blockIdx.x * TO;

    // stage A, mask (128 entries each), and transposed W (1024 weights)
    if (t < TO * MAXD) {
        Ash[t] = A[o0 * MAXD + t];
        Msh[t] = mask[o0 * MAXD + t];
    }
    for (int k = 0; k < 2; ++k) {
        const int idx = t + 512 * k;
        const int c = idx >> 5, cd = idx & 31;
        Wt[cd * 36 + c] = W[idx];
    }
    __syncthreads();

    // ---- phase 1: gather bf16 rows of xt (512B = full row per wave-instruction)
    // 8 wave-groups x 1 node each; ALL 16 loads issued before any consume.
    {
        const int j  = t & 63;                 // ushort4 column within row
        const int ol = t >> 6;                 // wave-group = node within block
        const ushort4* xt4 = (const ushort4*)xt;   // row pitch = 64 ushort4

        ushort4 u[MAXD];
#pragma unroll
        for (int d = 0; d < MAXD; ++d) {
            const int idx = Ash[ol * MAXD + d];   // wave-uniform -> broadcast
            u[d] = xt4[(size_t)idx * 64 + j];
        }
        float4 a = make_float4(0.f, 0.f, 0.f, 0.f);
#pragma unroll
        for (int d = 0; d < MAXD; ++d) {
            const float s = Msh[ol * MAXD + d];
            a.x += s * bf2f(u[d].x);
            a.y += s * bf2f(u[d].y);
            a.z += s * bf2f(u[d].z);
            a.w += s * bf2f(u[d].w);
        }
        *(float4*)&pooled[ol * 260 + 4 * j] = a;
    }
    __syncthreads();

    // ---- phase 2 (t<256 only): thread = (n, cd). 32-term dot per node,
    // each lane writes a 32B run of out. Phase 2 is ~1% of the kernel,
    // idling waves 4..7 here is free.
    if (t < 256) {
        const int n  = t >> 5;   // 0..7
        const int cd = t & 31;   // 0..31
        float4 w[8];
#pragma unroll
        for (int cc = 0; cc < 8; ++cc)
            w[cc] = *(const float4*)&Wt[cd * 36 + 4 * cc];

        float res[TO];
#pragma unroll
        for (int ol = 0; ol < TO; ++ol) {
            const float4* pr = (const float4*)&pooled[ol * 260 + n * 32];
            float s = 0.f;
#pragma unroll
            for (int cc = 0; cc < 8; ++cc) {
                const float4 p = pr[cc];       // 2 addrs/wave -> LDS broadcast
                s += p.x * w[cc].x + p.y * w[cc].y + p.z * w[cc].z + p.w * w[cc].w;
            }
            res[ol] = s;
        }

        const size_t obase = (size_t)n * (32 * OUTN) + (size_t)cd * OUTN + o0;
        const size_t bbase = (size_t)cd * OUTN + o0;
#pragma unroll
        for (int q = 0; q < 2; ++q) {
            const float4 b = *(const float4*)&bias[bbase + 4 * q];
            float4 r;
            r.x = res[4 * q + 0] + b.x;
            r.y = res[4 * q + 1] + b.y;
            r.z = res[4 * q + 2] + b.z;
            r.w = res[4 * q + 3] + b.w;
            *(float4*)&out[obase + 4 * q] = r;
        }
    }
}

extern "C" void kernel_launch(void* const* d_in, const int* in_sizes, int n_in,
                              void* d_out, int out_size, void* d_ws, size_t ws_size,
                              hipStream_t stream) {
    const float* x    = (const float*)d_in[0];
    const int*   A    = (const int*)  d_in[1];
    const float* mask = (const float*)d_in[2];
    const float* W    = (const float*)d_in[3];
    const float* bias = (const float*)d_in[4];
    float* out = (float*)d_out;
    unsigned short* xt = (unsigned short*)d_ws;   // 50000*256*2 = 25.6 MB scratch

    // K1: 782 i-tiles (ceil(50000/64)) x 4 r-tiles
    transpose_x<<<dim3(782, 4), 256, 0, stream>>>(x, xt);
    // K2: 8192/8 = 1024 blocks x 512 threads, 1 node per wave-group
    gather_gemm<<<OUTN / TO, 512, 0, stream>>>(xt, A, mask, W, bias, out);
}

// Round 3
// 113.029 us; speedup vs baseline: 1.0073x; 1.0073x over previous
//
#include <hip/hip_runtime.h>
#include <hip/hip_bf16.h>

// Problem constants (fixed by reference):
//   x[N=8][INC=32][INN=50000] fp32, A[OUTN=8192][MAXD=16] int32,
//   mask[OUTN][MAXD][1] fp32, weight[INC=32][OUTC=32] fp32, bias[OUTC=32][OUTN=8192]
//   out[N=8][OUTC=32][OUTN=8192] fp32
// K1: transpose x -> xt[INN][256] bf16 (row j = n*32+c).  K2: gather+pool+matmul fp32.
// R7b: identical to R7 (container infra failure, no verdict — resubmit for
//     measurement). R7 changes: (1) K2 TO=32 @1024thr: each phase-2 lane owns a
//     FULL 128B run of out (TO=8 wrote scattered 32B quarter-lines from
//     different blocks/XCDs -> HBM partial-line write amplification). 16
//     waves/CU preserved for gather latency hiding. (2) K1 stores 16B/lane
//     (8 bf16 packed in uint4) -> half the store+LDS-read instructions; LDS
//     gather stays 2-way bank-aliased (free). Numerics path unchanged.

#define INN   50000
#define NR    256        // N*INC rows
#define OUTN  8192
#define MAXD  16
#define TO    32         // output nodes per block in K2

static __device__ __forceinline__ float bf2f(unsigned short u) {
    return __uint_as_float(((unsigned int)u) << 16);
}

static __device__ __forceinline__ unsigned pack2(float a, float b) {
    const unsigned lo = (unsigned)__bfloat16_as_ushort(__float2bfloat16(a));
    const unsigned hi = (unsigned)__bfloat16_as_ushort(__float2bfloat16(b));
    return lo | (hi << 16);
}

// ---------------- Kernel 1: transpose x[256][50000] -> xt_bf16[50000][256] ----
// 64(i) x 64(r) tile, float4 loads along i, uint4 (bf16x8 = 16B) stores along r.
// LDS pitch 65: load-scatter and store-gather are <=2-way bank-aliased (free).
__global__ __launch_bounds__(256) void transpose_x(const float* __restrict__ x,
                                                   unsigned short* __restrict__ xt) {
    __shared__ float tile[64 * 65];
    const int t  = threadIdx.x;
    const int i0 = blockIdx.x * 64;   // column (INN) tile base
    const int r0 = blockIdx.y * 64;   // row tile base (always < 256)

    // ---- load: lanes sweep i (coalesced float4), 16 rows per k-step
    {
        const int i4l = t & 15;        // which float4 within the 64-wide i tile
        const int rl0 = t >> 4;        // row within tile
        const float4* x4 = (const float4*)x;
        const int i4base = (i0 >> 2) + i4l;
        const bool iv = (i4base < (INN / 4));   // INN % 4 == 0
        for (int k = 0; k < 4; ++k) {
            const int rl = rl0 + 16 * k;
            float4 v = iv ? x4[(size_t)(r0 + rl) * (INN / 4) + i4base]
                          : make_float4(0.f, 0.f, 0.f, 0.f);
            const int ib = i4l * 4;
            tile[(ib + 0) * 65 + rl] = v.x;
            tile[(ib + 1) * 65 + rl] = v.y;
            tile[(ib + 2) * 65 + rl] = v.z;
            tile[(ib + 3) * 65 + rl] = v.w;
        }
    }
    __syncthreads();
    // ---- store: lanes sweep r (coalesced 16B/lane = 8 bf16), 8 i-rows/wave
    {
        const int r8l = t & 7;         // which 8-ushort group within the 64 r
        const int il0 = t >> 3;        // 0..31
        for (int k = 0; k < 2; ++k) {
            const int il = il0 + 32 * k;
            const int i  = i0 + il;
            if (i < INN) {
                const float* src = &tile[il * 65 + r8l * 8];
                uint4 b;
                b.x = pack2(src[0], src[1]);
                b.y = pack2(src[2], src[3]);
                b.z = pack2(src[4], src[5]);
                b.w = pack2(src[6], src[7]);
                *(uint4*)&xt[(size_t)i * NR + r0 + 8 * r8l] = b;
            }
        }
    }
}

// ---------------- Kernel 2: gather + masked pool + 32x32 matmul + bias ------
// One block = 32 output nodes, 1024 threads (16 wave-groups x 2 nodes).
// Grid = 256 blocks -> 1 block/CU, 16 waves/CU during the gather phase.
// Phase 2 on t<256: each lane computes 32 consecutive-o outputs for its
// (n, cd) and writes a FULL 128B run of out (and reads 128B bias runs).
__global__ __launch_bounds__(1024) void gather_gemm(const unsigned short* __restrict__ xt,
                                                    const int*   __restrict__ A,
                                                    const float* __restrict__ mask,
                                                    const float* __restrict__ W,
                                                    const float* __restrict__ bias,
                                                    float* __restrict__ out) {
    // pooled pitch 260: 16B-aligned rows; every LDS op <=2-way aliased (free).
    __shared__ float pooled[TO * 260];   // 33.3 KB
    __shared__ float Wt[32 * 36];        // Wt[cd][c], pitch 36 (16B aligned rows)
    __shared__ int   Ash[TO * MAXD];     // 512
    __shared__ float Msh[TO * MAXD];

    const int t  = threadIdx.x;
    const int o0 = blockIdx.x * TO;

    // stage A, mask (512 entries each), and transposed W (1024 weights)
    if (t < TO * MAXD) {
        Ash[t] = A[o0 * MAXD + t];
        Msh[t] = mask[o0 * MAXD + t];
    }
    {
        const int c = t >> 5, cd = t & 31;
        Wt[cd * 36 + c] = W[t];          // t covers all 1024 weights
    }
    __syncthreads();

    // ---- phase 1: gather bf16 rows of xt (512B = full row per wave-instruction)
    // 16 wave-groups x 2 nodes each; all 16 row loads issued before any consume.
    {
        const int j  = t & 63;                 // ushort4 column within row
        const int og = t >> 6;                 // 16 wave-groups
        const ushort4* xt4 = (const ushort4*)xt;   // row pitch = 64 ushort4
        for (int m = 0; m < 2; ++m) {
            const int ol = og * 2 + m;
            ushort4 u[MAXD];
#pragma unroll
            for (int d = 0; d < MAXD; ++d) {
                const int idx = Ash[ol * MAXD + d];   // wave-uniform -> broadcast
                u[d] = xt4[(size_t)idx * 64 + j];
            }
            float4 a = make_float4(0.f, 0.f, 0.f, 0.f);
#pragma unroll
            for (int d = 0; d < MAXD; ++d) {
                const float s = Msh[ol * MAXD + d];
                a.x += s * bf2f(u[d].x);
                a.y += s * bf2f(u[d].y);
                a.z += s * bf2f(u[d].z);
                a.w += s * bf2f(u[d].w);
            }
            *(float4*)&pooled[ol * 260 + 4 * j] = a;
        }
    }
    __syncthreads();

    // ---- phase 2 (t<256 only): thread = (n, cd). 32-term dot per node,
    // each lane writes a full 128B run of out. Phase 2 is ~1% of the kernel,
    // idling waves 4..15 here is free.
    if (t < 256) {
        const int n  = t >> 5;   // 0..7
        const int cd = t & 31;   // 0..31
        float4 w[8];
#pragma unroll
        for (int cc = 0; cc < 8; ++cc)
            w[cc] = *(const float4*)&Wt[cd * 36 + 4 * cc];

        float res[TO];
#pragma unroll
        for (int ol = 0; ol < TO; ++ol) {
            const float4* pr = (const float4*)&pooled[ol * 260 + n * 32];
            float s = 0.f;
#pragma unroll
            for (int cc = 0; cc < 8; ++cc) {
                const float4 p = pr[cc];       // few addrs/wave -> LDS broadcast
                s += p.x * w[cc].x + p.y * w[cc].y + p.z * w[cc].z + p.w * w[cc].w;
            }
            res[ol] = s;
        }

        const size_t obase = (size_t)n * (32 * OUTN) + (size_t)cd * OUTN + o0;
        const size_t bbase = (size_t)cd * OUTN + o0;
#pragma unroll
        for (int q = 0; q < 8; ++q) {
            const float4 b = *(const float4*)&bias[bbase + 4 * q];
            float4 r;
            r.x = res[4 * q + 0] + b.x;
            r.y = res[4 * q + 1] + b.y;
            r.z = res[4 * q + 2] + b.z;
            r.w = res[4 * q + 3] + b.w;
            *(float4*)&out[obase + 4 * q] = r;
        }
    }
}

extern "C" void kernel_launch(void* const* d_in, const int* in_sizes, int n_in,
                              void* d_out, int out_size, void* d_ws, size_t ws_size,
                              hipStream_t stream) {
    const float* x    = (const float*)d_in[0];
    const int*   A    = (const int*)  d_in[1];
    const float* mask = (const float*)d_in[2];
    const float* W    = (const float*)d_in[3];
    const float* bias = (const float*)d_in[4];
    float* out = (float*)d_out;
    unsigned short* xt = (unsigned short*)d_ws;   // 50000*256*2 = 25.6 MB scratch

    // K1: 782 i-tiles (ceil(50000/64)) x 4 r-tiles
    transpose_x<<<dim3(782, 4), 256, 0, stream>>>(x, xt);
    // K2: 8192/32 = 256 blocks x 1024 threads, 2 nodes per wave-group
    gather_gemm<<<OUTN / TO, 1024, 0, stream>>>(xt, A, mask, W, bias, out);
}